// Round 5
// baseline (245.216 us; speedup 1.0000x reference)
//
#include <hip/hip_runtime.h>

#define HDIM 1024
#define NW 18                 // 6 gate rows + 12 expert rows (e*2+l)
#define WSTRIDE 19            // padded f32x4 stride -> 2-way-only bank aliasing for 16-lane clusters
#define NTHREADS 256
#define RPT 8                 // rows per lane
#define CL 16                 // lanes per cluster (256B contiguous per row-chunk)
#define NCL 4                 // clusters per wave
#define ROWS_PER_WAVE (NCL * RPT)        // 32
#define ROWS_PER_BLOCK (4 * ROWS_PER_WAVE) // 128
#define NJ (HDIM / (CL * 4))  // 16 j-steps, 64 cols each

typedef float f32x4 __attribute__((ext_vector_type(4)));

// R5: test of DRAM stream-granularity theory.
//  - 16-lane clusters: each x-load instruction reads 4 rows x 256B contiguous
//    (vs 8 rows x 128B in R3/R4) -> half the concurrent DRAM streams, double chunk.
//  - RPT=8 keeps LDS broadcast reads at 9 per row (~11.5 us/CU, well under HBM).
//  - grid 512, 2 blocks/CU (152KB LDS), ~240 VGPR -> 2 waves/SIMD.
//  - Weights in LDS [slot 0..255][w 0..17] with padded stride 19 f32x4:
//    16 c-addresses per read -> 2 lanes/bank, 2 distinct addrs/bank = ~free.
__global__ __launch_bounds__(NTHREADS, 2)
void hardmoe_kernel(const float* __restrict__ cls,
                    const float* __restrict__ gate_w,
                    const float* __restrict__ gate_b,
                    const float* __restrict__ expert_w,
                    const float* __restrict__ expert_b,
                    float* __restrict__ out, int B)
{
    __shared__ f32x4 Wl[256 * WSTRIDE];   // 76 KB

    const int t = threadIdx.x;

    // ---- Stage weights: thread t owns f4-slot s=t for all 18 w ----
    {
        const int s = t;
#pragma unroll
        for (int w = 0; w < NW; ++w) {
            const float* src = (w < 6) ? (gate_w + (size_t)w * HDIM)
                                       : (expert_w + (size_t)(w - 6) * HDIM);
            Wl[s * WSTRIDE + w] = *(reinterpret_cast<const f32x4*>(src) + s);
        }
    }

    // ---- Biases (uniform -> scalar) ----
    float gb[6], eb[12];
#pragma unroll
    for (int e = 0; e < 6; ++e) gb[e] = gate_b[e];
#pragma unroll
    for (int k = 0; k < 12; ++k) eb[k] = expert_b[k];

    __syncthreads();

    const int wv = t >> 6;        // wave 0..3
    const int l  = t & 63;
    const int cl = l >> 4;        // cluster 0..3
    const int c  = l & 15;        // col sublane 0..15

    const int wavebase = blockIdx.x * ROWS_PER_BLOCK + wv * ROWS_PER_WAVE;

    const float* px[RPT];
    int rows[RPT];
#pragma unroll
    for (int k = 0; k < RPT; ++k) {
        int r = wavebase + k * NCL + cl;
        rows[k] = r;
        int rc = r < B ? r : B - 1;
        px[k] = cls + (size_t)rc * HDIM + c * 4;
    }

    float acc[RPT][NW];
#pragma unroll
    for (int k = 0; k < RPT; ++k)
#pragma unroll
        for (int w = 0; w < NW; ++w) acc[k][w] = 0.f;

    f32x4 xA[RPT], xB[RPT];
#pragma unroll
    for (int k = 0; k < RPT; ++k)
        xA[k] = __builtin_nontemporal_load(reinterpret_cast<const f32x4*>(px[k]));

    for (int j = 0; j < NJ; j += 2) {
        // prefetch j+1
#pragma unroll
        for (int k = 0; k < RPT; ++k)
            xB[k] = __builtin_nontemporal_load(
                reinterpret_cast<const f32x4*>(px[k] + (size_t)(j + 1) * (CL * 4)));
        // compute j with xA
        {
            const f32x4* wp = &Wl[(j * CL + c) * WSTRIDE];
#pragma unroll
            for (int w = 0; w < NW; ++w) {
                f32x4 wf = wp[w];
#pragma unroll
                for (int k = 0; k < RPT; ++k) {
                    float a = acc[k][w];
                    a = fmaf(xA[k].x, wf.x, a);
                    a = fmaf(xA[k].y, wf.y, a);
                    a = fmaf(xA[k].z, wf.z, a);
                    a = fmaf(xA[k].w, wf.w, a);
                    acc[k][w] = a;
                }
            }
        }
        // prefetch j+2
        if (j + 2 < NJ) {
#pragma unroll
            for (int k = 0; k < RPT; ++k)
                xA[k] = __builtin_nontemporal_load(
                    reinterpret_cast<const f32x4*>(px[k] + (size_t)(j + 2) * (CL * 4)));
        }
        // compute j+1 with xB
        {
            const f32x4* wq = &Wl[((j + 1) * CL + c) * WSTRIDE];
#pragma unroll
            for (int w = 0; w < NW; ++w) {
                f32x4 wf = wq[w];
#pragma unroll
                for (int k = 0; k < RPT; ++k) {
                    float a = acc[k][w];
                    a = fmaf(xB[k].x, wf.x, a);
                    a = fmaf(xB[k].y, wf.y, a);
                    a = fmaf(xB[k].z, wf.z, a);
                    a = fmaf(xB[k].w, wf.w, a);
                    acc[k][w] = a;
                }
            }
        }
    }

    // ---- Reduce across the 16-lane cluster: xor 1,2,4,8 ----
#pragma unroll
    for (int k = 0; k < RPT; ++k)
#pragma unroll
        for (int w = 0; w < NW; ++w) {
            float v = acc[k][w];
            v += __shfl_xor(v, 1);
            v += __shfl_xor(v, 2);
            v += __shfl_xor(v, 4);
            v += __shfl_xor(v, 8);
            acc[k][w] = v;
        }

    // ---- Per row: gate argmax (strict >, first-max tiebreak) + expert select ----
#pragma unroll
    for (int k = 0; k < RPT; ++k) {
        float best = acc[k][0] + gb[0];
        int idx = 0;
#pragma unroll
        for (int e = 1; e < 6; ++e) {
            float v = acc[k][e] + gb[e];
            if (v > best) { best = v; idx = e; }
        }
        float o0 = 0.f, o1 = 0.f;
#pragma unroll
        for (int e = 0; e < 6; ++e) {
            bool m = (idx == e);
            o0 = m ? (acc[k][6 + 2 * e] + eb[2 * e])     : o0;
            o1 = m ? (acc[k][7 + 2 * e] + eb[2 * e + 1]) : o1;
        }
        if (c == 0 && rows[k] < B)
            *reinterpret_cast<float2*>(out + (size_t)rows[k] * 2) = make_float2(o0, o1);
    }
}

extern "C" void kernel_launch(void* const* d_in, const int* in_sizes, int n_in,
                              void* d_out, int out_size, void* d_ws, size_t ws_size,
                              hipStream_t stream) {
    const float* cls      = (const float*)d_in[0];
    const float* gate_w   = (const float*)d_in[1];
    const float* gate_b   = (const float*)d_in[2];
    const float* expert_w = (const float*)d_in[3];
    const float* expert_b = (const float*)d_in[4];
    float* out = (float*)d_out;

    const int B = in_sizes[0] / HDIM;
    const int grid = (B + ROWS_PER_BLOCK - 1) / ROWS_PER_BLOCK;

    hardmoe_kernel<<<grid, NTHREADS, 0, stream>>>(cls, gate_w, gate_b,
                                                  expert_w, expert_b, out, B);
}

// Round 6
// 73.411 us; speedup vs baseline: 3.3403x; 3.3403x over previous
//
#include <hip/hip_runtime.h>

#define HDIM 1024
#define NW 18                 // 6 gate rows + 12 expert rows (e*2+l)
#define WSTRIDE 19            // padded f32x4 stride -> 2-way-only bank aliasing for 16-lane clusters
#define NTHREADS 256
#define RPT 8                 // rows per lane
#define CL 16                 // lanes per cluster (256B contiguous per row-chunk)
#define NCL 4                 // clusters per wave
#define ROWS_PER_WAVE (NCL * RPT)          // 32
#define ROWS_PER_BLOCK (4 * ROWS_PER_WAVE) // 128
#define NJ (HDIM / (CL * 4))  // 16 j-steps, 64 cols each

typedef float f32x4 __attribute__((ext_vector_type(4)));

// R6: unconfounded DRAM stream-granularity test (R5 minus the spill).
//  - Identical to R3's proven structure (RPT=8, LDS-broadcast weights, nt x stream,
//    distance-1 double-buffer) EXCEPT clusters are 16 lanes -> each row-stream
//    advances in 256B contiguous chunks (R3: 128B).
//  - __launch_bounds__(256,1): ~250 VGPR live, NO spill (R5's (256,2) capped VGPR
//    at 128 -> 441MB of scratch spill traffic, the entire regression).
//  - grid 512 -> 2 sequential blocks/CU (tail balancing), 76KB LDS, 1 wave/SIMD.
__global__ __launch_bounds__(NTHREADS, 1)
void hardmoe_kernel(const float* __restrict__ cls,
                    const float* __restrict__ gate_w,
                    const float* __restrict__ gate_b,
                    const float* __restrict__ expert_w,
                    const float* __restrict__ expert_b,
                    float* __restrict__ out, int B)
{
    __shared__ f32x4 Wl[256 * WSTRIDE];   // 76 KB

    const int t = threadIdx.x;

    // ---- Stage weights: thread t owns f4-slot s=t for all 18 w ----
    {
        const int s = t;
#pragma unroll
        for (int w = 0; w < NW; ++w) {
            const float* src = (w < 6) ? (gate_w + (size_t)w * HDIM)
                                       : (expert_w + (size_t)(w - 6) * HDIM);
            Wl[s * WSTRIDE + w] = *(reinterpret_cast<const f32x4*>(src) + s);
        }
    }

    // ---- Biases (uniform -> scalar) ----
    float gb[6], eb[12];
#pragma unroll
    for (int e = 0; e < 6; ++e) gb[e] = gate_b[e];
#pragma unroll
    for (int k = 0; k < 12; ++k) eb[k] = expert_b[k];

    __syncthreads();

    const int wv = t >> 6;        // wave 0..3
    const int l  = t & 63;
    const int cl = l >> 4;        // cluster 0..3
    const int c  = l & 15;        // col sublane 0..15

    const int wavebase = blockIdx.x * ROWS_PER_BLOCK + wv * ROWS_PER_WAVE;

    const float* px[RPT];
    int rows[RPT];
#pragma unroll
    for (int k = 0; k < RPT; ++k) {
        int r = wavebase + k * NCL + cl;
        rows[k] = r;
        int rc = r < B ? r : B - 1;
        px[k] = cls + (size_t)rc * HDIM + c * 4;
    }

    float acc[RPT][NW];
#pragma unroll
    for (int k = 0; k < RPT; ++k)
#pragma unroll
        for (int w = 0; w < NW; ++w) acc[k][w] = 0.f;

    f32x4 xA[RPT], xB[RPT];
#pragma unroll
    for (int k = 0; k < RPT; ++k)
        xA[k] = __builtin_nontemporal_load(reinterpret_cast<const f32x4*>(px[k]));

    for (int j = 0; j < NJ; j += 2) {
        // prefetch j+1
#pragma unroll
        for (int k = 0; k < RPT; ++k)
            xB[k] = __builtin_nontemporal_load(
                reinterpret_cast<const f32x4*>(px[k] + (size_t)(j + 1) * (CL * 4)));
        // compute j with xA
        {
            const f32x4* wp = &Wl[(j * CL + c) * WSTRIDE];
#pragma unroll
            for (int w = 0; w < NW; ++w) {
                f32x4 wf = wp[w];
#pragma unroll
                for (int k = 0; k < RPT; ++k) {
                    float a = acc[k][w];
                    a = fmaf(xA[k].x, wf.x, a);
                    a = fmaf(xA[k].y, wf.y, a);
                    a = fmaf(xA[k].z, wf.z, a);
                    a = fmaf(xA[k].w, wf.w, a);
                    acc[k][w] = a;
                }
            }
        }
        // prefetch j+2
        if (j + 2 < NJ) {
#pragma unroll
            for (int k = 0; k < RPT; ++k)
                xA[k] = __builtin_nontemporal_load(
                    reinterpret_cast<const f32x4*>(px[k] + (size_t)(j + 2) * (CL * 4)));
        }
        // compute j+1 with xB
        {
            const f32x4* wq = &Wl[((j + 1) * CL + c) * WSTRIDE];
#pragma unroll
            for (int w = 0; w < NW; ++w) {
                f32x4 wf = wq[w];
#pragma unroll
                for (int k = 0; k < RPT; ++k) {
                    float a = acc[k][w];
                    a = fmaf(xB[k].x, wf.x, a);
                    a = fmaf(xB[k].y, wf.y, a);
                    a = fmaf(xB[k].z, wf.z, a);
                    a = fmaf(xB[k].w, wf.w, a);
                    acc[k][w] = a;
                }
            }
        }
    }

    // ---- Reduce across the 16-lane cluster: xor 1,2,4,8 ----
#pragma unroll
    for (int k = 0; k < RPT; ++k)
#pragma unroll
        for (int w = 0; w < NW; ++w) {
            float v = acc[k][w];
            v += __shfl_xor(v, 1);
            v += __shfl_xor(v, 2);
            v += __shfl_xor(v, 4);
            v += __shfl_xor(v, 8);
            acc[k][w] = v;
        }

    // ---- Per row: gate argmax (strict >, first-max tiebreak) + expert select ----
#pragma unroll
    for (int k = 0; k < RPT; ++k) {
        float best = acc[k][0] + gb[0];
        int idx = 0;
#pragma unroll
        for (int e = 1; e < 6; ++e) {
            float v = acc[k][e] + gb[e];
            if (v > best) { best = v; idx = e; }
        }
        float o0 = 0.f, o1 = 0.f;
#pragma unroll
        for (int e = 0; e < 6; ++e) {
            bool m = (idx == e);
            o0 = m ? (acc[k][6 + 2 * e] + eb[2 * e])     : o0;
            o1 = m ? (acc[k][7 + 2 * e] + eb[2 * e + 1]) : o1;
        }
        if (c == 0 && rows[k] < B)
            *reinterpret_cast<float2*>(out + (size_t)rows[k] * 2) = make_float2(o0, o1);
    }
}

extern "C" void kernel_launch(void* const* d_in, const int* in_sizes, int n_in,
                              void* d_out, int out_size, void* d_ws, size_t ws_size,
                              hipStream_t stream) {
    const float* cls      = (const float*)d_in[0];
    const float* gate_w   = (const float*)d_in[1];
    const float* gate_b   = (const float*)d_in[2];
    const float* expert_w = (const float*)d_in[3];
    const float* expert_b = (const float*)d_in[4];
    float* out = (float*)d_out;

    const int B = in_sizes[0] / HDIM;
    const int grid = (B + ROWS_PER_BLOCK - 1) / ROWS_PER_BLOCK;

    hardmoe_kernel<<<grid, NTHREADS, 0, stream>>>(cls, gate_w, gate_b,
                                                  expert_w, expert_b, out, B);
}

// Round 7
// 56.175 us; speedup vs baseline: 4.3652x; 1.3068x over previous
//
#include <hip/hip_runtime.h>

#define HDIM 1024
#define NW 18                 // 6 gate rows + 12 expert rows (e*2+l)
#define NTHREADS 256
#define RPT 8                 // rows per lane
#define ROWS_PER_BLOCK 256    // 4 waves x 64 rows
#define NJ 32                 // j-steps of 32 floats (128B) per row

typedef float f32x4 __attribute__((ext_vector_type(4)));

// R7 = R3 (best so far, 64.9us) + per-wave column-phase rotation.
//  - Theory: 4KB row stride + machine-wide lockstep column advance = DRAM channel
//    camping (all streams hit the same channel slot each instant). Rotating each
//    wave's j-start phase decorrelates channel usage at ~zero cost.
//  - Everything else identical to R3: 8-lane clusters (128B chunks), RPT=8,
//    LDS-broadcast weights [slot 0..255][w 0..17] f32x4 (72KB), nt x loads,
//    distance-1 static double buffer, launch_bounds(256,1), grid 256.
__global__ __launch_bounds__(NTHREADS, 1)
void hardmoe_kernel(const float* __restrict__ cls,
                    const float* __restrict__ gate_w,
                    const float* __restrict__ gate_b,
                    const float* __restrict__ expert_w,
                    const float* __restrict__ expert_b,
                    float* __restrict__ out, int B)
{
    __shared__ f32x4 Wl[256 * NW];   // 72 KB

    const int t = threadIdx.x;

    // ---- Stage weights: thread t owns f4-slot s=t for all 18 w ----
    {
        const int s = t;
#pragma unroll
        for (int w = 0; w < NW; ++w) {
            const float* src = (w < 6) ? (gate_w + (size_t)w * HDIM)
                                       : (expert_w + (size_t)(w - 6) * HDIM);
            Wl[s * NW + w] = *(reinterpret_cast<const f32x4*>(src) + s);
        }
    }

    // ---- Biases (uniform -> scalar) ----
    float gb[6], eb[12];
#pragma unroll
    for (int e = 0; e < 6; ++e) gb[e] = gate_b[e];
#pragma unroll
    for (int k = 0; k < 12; ++k) eb[k] = expert_b[k];

    __syncthreads();

    const int wv = t >> 6;       // wave 0..3
    const int l  = t & 63;
    const int s8 = l >> 3;       // cluster 0..7
    const int c  = l & 7;        // col sublane 0..7

    // Even phase in [0,32), spread over blocks and waves:
    // (8*block + 2*wave) mod 32 -> 16 distinct even phases, uniform machine-wide.
    const int phase = ((blockIdx.x << 3) + (wv << 1)) & (NJ - 1);

    const int wavebase = blockIdx.x * ROWS_PER_BLOCK + wv * 64;

    const float* px[RPT];
    int rows[RPT];
#pragma unroll
    for (int k = 0; k < RPT; ++k) {
        int r = wavebase + k * 8 + s8;
        rows[k] = r;
        int rc = r < B ? r : B - 1;
        px[k] = cls + (size_t)rc * HDIM + c * 4;
    }

    float acc[RPT][NW];
#pragma unroll
    for (int k = 0; k < RPT; ++k)
#pragma unroll
        for (int w = 0; w < NW; ++w) acc[k][w] = 0.f;

    f32x4 xA[RPT], xB[RPT];
#pragma unroll
    for (int k = 0; k < RPT; ++k)
        xA[k] = __builtin_nontemporal_load(
            reinterpret_cast<const f32x4*>(px[k] + (size_t)phase * 32));

    for (int jj = 0; jj < NJ; jj += 2) {
        const int ja = (jj + phase) & (NJ - 1);
        const int jb = (jj + 1 + phase) & (NJ - 1);
        const int jc = (jj + 2 + phase) & (NJ - 1);

        // prefetch column jb
#pragma unroll
        for (int k = 0; k < RPT; ++k)
            xB[k] = __builtin_nontemporal_load(
                reinterpret_cast<const f32x4*>(px[k] + (size_t)jb * 32));
        // compute column ja with xA
        {
            const f32x4* wp = &Wl[(ja * 8 + c) * NW];
#pragma unroll
            for (int w = 0; w < NW; ++w) {
                f32x4 wf = wp[w];
#pragma unroll
                for (int k = 0; k < RPT; ++k) {
                    float a = acc[k][w];
                    a = fmaf(xA[k].x, wf.x, a);
                    a = fmaf(xA[k].y, wf.y, a);
                    a = fmaf(xA[k].z, wf.z, a);
                    a = fmaf(xA[k].w, wf.w, a);
                    acc[k][w] = a;
                }
            }
        }
        // prefetch column jc
        if (jj + 2 < NJ) {
#pragma unroll
            for (int k = 0; k < RPT; ++k)
                xA[k] = __builtin_nontemporal_load(
                    reinterpret_cast<const f32x4*>(px[k] + (size_t)jc * 32));
        }
        // compute column jb with xB
        {
            const f32x4* wq = &Wl[(jb * 8 + c) * NW];
#pragma unroll
            for (int w = 0; w < NW; ++w) {
                f32x4 wf = wq[w];
#pragma unroll
                for (int k = 0; k < RPT; ++k) {
                    float a = acc[k][w];
                    a = fmaf(xB[k].x, wf.x, a);
                    a = fmaf(xB[k].y, wf.y, a);
                    a = fmaf(xB[k].z, wf.z, a);
                    a = fmaf(xB[k].w, wf.w, a);
                    acc[k][w] = a;
                }
            }
        }
    }

    // ---- Reduce across the 8-lane cluster: xor 1,2,4 ----
#pragma unroll
    for (int k = 0; k < RPT; ++k)
#pragma unroll
        for (int w = 0; w < NW; ++w) {
            float v = acc[k][w];
            v += __shfl_xor(v, 1);
            v += __shfl_xor(v, 2);
            v += __shfl_xor(v, 4);
            acc[k][w] = v;
        }

    // ---- Per row: gate argmax (strict >, first-max tiebreak) + expert select ----
#pragma unroll
    for (int k = 0; k < RPT; ++k) {
        float best = acc[k][0] + gb[0];
        int idx = 0;
#pragma unroll
        for (int e = 1; e < 6; ++e) {
            float v = acc[k][e] + gb[e];
            if (v > best) { best = v; idx = e; }
        }
        float o0 = 0.f, o1 = 0.f;
#pragma unroll
        for (int e = 0; e < 6; ++e) {
            bool m = (idx == e);
            o0 = m ? (acc[k][6 + 2 * e] + eb[2 * e])     : o0;
            o1 = m ? (acc[k][7 + 2 * e] + eb[2 * e + 1]) : o1;
        }
        if (c == 0 && rows[k] < B)
            *reinterpret_cast<float2*>(out + (size_t)rows[k] * 2) = make_float2(o0, o1);
    }
}

extern "C" void kernel_launch(void* const* d_in, const int* in_sizes, int n_in,
                              void* d_out, int out_size, void* d_ws, size_t ws_size,
                              hipStream_t stream) {
    const float* cls      = (const float*)d_in[0];
    const float* gate_w   = (const float*)d_in[1];
    const float* gate_b   = (const float*)d_in[2];
    const float* expert_w = (const float*)d_in[3];
    const float* expert_b = (const float*)d_in[4];
    float* out = (float*)d_out;

    const int B = in_sizes[0] / HDIM;
    const int grid = (B + ROWS_PER_BLOCK - 1) / ROWS_PER_BLOCK;

    hardmoe_kernel<<<grid, NTHREADS, 0, stream>>>(cls, gate_w, gate_b,
                                                  expert_w, expert_b, out, B);
}